// Round 1
// baseline (1387.243 us; speedup 1.0000x reference)
//
#include <hip/hip_runtime.h>

#define T_TOKENS 8192
#define D_MODEL  1024
#define D_FF     4096
#define N_EXP    8

#define BM 128
#define BN 128
#define BK 32
#define SP 40   // padded LDS row stride in bf16 elements (80 B: 16B-aligned, spreads bank groups)

typedef __attribute__((ext_vector_type(8))) short bf16x8;
typedef __attribute__((ext_vector_type(4))) float f32x4;

__device__ __forceinline__ unsigned short f2bf(float f) {
    unsigned int u = __float_as_uint(f);
    u += 0x7fffu + ((u >> 16) & 1u);   // RNE
    return (unsigned short)(u >> 16);
}

// ---------------- router: logits, top-2, softmax, counts ----------------
__global__ void router_kernel(const float* __restrict__ x, const float* __restrict__ gW,
                              const float* __restrict__ gb, int* __restrict__ counts,
                              int* __restrict__ top_e, float* __restrict__ top_p) {
    int t    = blockIdx.x * 4 + (threadIdx.x >> 6);
    int lane = threadIdx.x & 63;
    const float* xr = x + (size_t)t * D_MODEL;
    float acc[N_EXP];
#pragma unroll
    for (int e = 0; e < N_EXP; e++) acc[e] = 0.f;
    for (int i = 0; i < D_MODEL / 64; i++) {
        float xv = xr[lane + i * 64];
#pragma unroll
        for (int e = 0; e < N_EXP; e++) acc[e] += xv * gW[e * D_MODEL + lane + i * 64];
    }
#pragma unroll
    for (int e = 0; e < N_EXP; e++) {
#pragma unroll
        for (int off = 32; off > 0; off >>= 1) acc[e] += __shfl_down(acc[e], off, 64);
    }
    if (lane == 0) {
#pragma unroll
        for (int e = 0; e < N_EXP; e++) acc[e] += gb[e];
        int e0 = 0;
#pragma unroll
        for (int e = 1; e < N_EXP; e++) if (acc[e] > acc[e0]) e0 = e;  // ties -> lowest idx, matches lax.top_k
        int e1 = (e0 == 0) ? 1 : 0;
#pragma unroll
        for (int e = 0; e < N_EXP; e++) if (e != e0 && e != e1 && acc[e] > acc[e1]) e1 = e;
        float z1 = __expf(acc[e1] - acc[e0]);
        float s  = 1.f + z1;
        top_e[t * 2]     = e0;
        top_e[t * 2 + 1] = e1;
        top_p[t * 2]     = 1.f / s;
        top_p[t * 2 + 1] = z1 / s;
        atomicAdd(&counts[e0], 1);
        atomicAdd(&counts[e1], 1);
    }
}

__global__ void prefix_kernel(const int* __restrict__ counts, int* __restrict__ offsets,
                              int* __restrict__ cursor) {
    if (threadIdx.x == 0) {
        int s = 0;
        for (int e = 0; e < N_EXP; e++) { offsets[e] = s; cursor[e] = s; s += counts[e]; }
    }
}

__global__ void scatter_kernel(const int* __restrict__ top_e, const float* __restrict__ top_p,
                               int* __restrict__ cursor, int* __restrict__ row_map,
                               float* __restrict__ row_prob) {
    int t = blockIdx.x * 256 + threadIdx.x;
#pragma unroll
    for (int j = 0; j < 2; j++) {
        int e  = top_e[t * 2 + j];
        int pos = atomicAdd(&cursor[e], 1);
        row_map[pos]  = t;
        row_prob[pos] = top_p[t * 2 + j];
    }
}

// ---------------- gemm1: h = silu(x@Wg^T) * (x@W1^T), gathered rows, bf16 out -------------
__launch_bounds__(256, 2)
__global__ void gemm1_kernel(const float* __restrict__ x, const float* __restrict__ Wg,
                             const float* __restrict__ W1, const int* __restrict__ counts,
                             const int* __restrict__ offsets, const int* __restrict__ row_map,
                             unsigned short* __restrict__ hbuf) {
    int e   = blockIdx.z;
    int cnt = counts[e];
    int m0  = blockIdx.y * BM;
    if (m0 >= cnt) return;
    int base = offsets[e];
    int n0   = blockIdx.x * BN;
    int tid  = threadIdx.x;

    __shared__ unsigned short As[BM * SP];
    __shared__ unsigned short Bg[BN * SP];
    __shared__ unsigned short Bv[BN * SP];
    __shared__ int rowIdx[BM];

    if (tid < BM) {
        int i = m0 + tid;
        if (i > cnt - 1) i = cnt - 1;
        rowIdx[tid] = row_map[base + i];
    }
    __syncthreads();

    const float* wg = Wg + (size_t)e * D_FF * D_MODEL;
    const float* w1 = W1 + (size_t)e * D_FF * D_MODEL;

    int wave = tid >> 6, lane = tid & 63;
    int wm = (wave >> 1) * 64, wn = (wave & 1) * 64;
    int lm = lane & 15, lq = lane >> 4;

    f32x4 accG[4][4], accV[4][4];
#pragma unroll
    for (int i = 0; i < 4; i++)
#pragma unroll
        for (int j = 0; j < 4; j++) { accG[i][j] = (f32x4)0.f; accV[i][j] = (f32x4)0.f; }

    for (int kk = 0; kk < D_MODEL; kk += BK) {
#pragma unroll
        for (int l = 0; l < 4; l++) {
            int idx = tid + l * 256;
            int r = idx >> 3, s = idx & 7;
            float4 v = *(const float4*)(x + (size_t)rowIdx[r] * D_MODEL + kk + s * 4);
            unsigned short* d = &As[r * SP + s * 4];
            d[0] = f2bf(v.x); d[1] = f2bf(v.y); d[2] = f2bf(v.z); d[3] = f2bf(v.w);
        }
#pragma unroll
        for (int l = 0; l < 4; l++) {
            int idx = tid + l * 256;
            int r = idx >> 3, s = idx & 7;
            float4 v = *(const float4*)(wg + (size_t)(n0 + r) * D_MODEL + kk + s * 4);
            unsigned short* d = &Bg[r * SP + s * 4];
            d[0] = f2bf(v.x); d[1] = f2bf(v.y); d[2] = f2bf(v.z); d[3] = f2bf(v.w);
        }
#pragma unroll
        for (int l = 0; l < 4; l++) {
            int idx = tid + l * 256;
            int r = idx >> 3, s = idx & 7;
            float4 v = *(const float4*)(w1 + (size_t)(n0 + r) * D_MODEL + kk + s * 4);
            unsigned short* d = &Bv[r * SP + s * 4];
            d[0] = f2bf(v.x); d[1] = f2bf(v.y); d[2] = f2bf(v.z); d[3] = f2bf(v.w);
        }
        __syncthreads();

        bf16x8 aF[4], bgF[4], bvF[4];
#pragma unroll
        for (int mi = 0; mi < 4; mi++)
            aF[mi] = *(const bf16x8*)&As[(wm + mi * 16 + lm) * SP + lq * 8];
#pragma unroll
        for (int ni = 0; ni < 4; ni++) {
            bgF[ni] = *(const bf16x8*)&Bg[(wn + ni * 16 + lm) * SP + lq * 8];
            bvF[ni] = *(const bf16x8*)&Bv[(wn + ni * 16 + lm) * SP + lq * 8];
        }
#pragma unroll
        for (int mi = 0; mi < 4; mi++)
#pragma unroll
            for (int ni = 0; ni < 4; ni++) {
                accG[mi][ni] = __builtin_amdgcn_mfma_f32_16x16x32_bf16(aF[mi], bgF[ni], accG[mi][ni], 0, 0, 0);
                accV[mi][ni] = __builtin_amdgcn_mfma_f32_16x16x32_bf16(aF[mi], bvF[ni], accV[mi][ni], 0, 0, 0);
            }
        __syncthreads();
    }

    size_t hrow_base = (size_t)(base + m0);
#pragma unroll
    for (int mi = 0; mi < 4; mi++) {
#pragma unroll
        for (int r = 0; r < 4; r++) {
            int mrow = wm + mi * 16 + lq * 4 + r;
            if (m0 + mrow < cnt) {
                unsigned short* hp = hbuf + (hrow_base + mrow) * D_FF + n0 + wn;
#pragma unroll
                for (int ni = 0; ni < 4; ni++) {
                    float g = accG[mi][ni][r], v = accV[mi][ni][r];
                    float sg = g / (1.f + __expf(-g));
                    hp[ni * 16 + lm] = f2bf(sg * v);
                }
            }
        }
    }
}

// ---------------- gemm2: out[token] += prob * (h @ W2^T) ----------------
__launch_bounds__(256, 2)
__global__ void gemm2_kernel(const unsigned short* __restrict__ hbuf, const float* __restrict__ W2,
                             const int* __restrict__ counts, const int* __restrict__ offsets,
                             const int* __restrict__ row_map, const float* __restrict__ row_prob,
                             float* __restrict__ out) {
    int e   = blockIdx.z;
    int cnt = counts[e];
    int m0  = blockIdx.y * BM;
    if (m0 >= cnt) return;
    int base = offsets[e];
    int n0   = blockIdx.x * BN;
    int tid  = threadIdx.x;

    __shared__ unsigned short As[BM * SP];
    __shared__ unsigned short Bs[BN * SP];
    __shared__ int   tok[BM];
    __shared__ float prb[BM];

    if (tid < BM) {
        int i = m0 + tid;
        if (i > cnt - 1) i = cnt - 1;
        tok[tid] = row_map[base + i];
        prb[tid] = row_prob[base + i];
    }
    __syncthreads();

    const float* w2 = W2 + (size_t)e * D_MODEL * D_FF;

    int wave = tid >> 6, lane = tid & 63;
    int wm = (wave >> 1) * 64, wn = (wave & 1) * 64;
    int lm = lane & 15, lq = lane >> 4;

    f32x4 acc[4][4];
#pragma unroll
    for (int i = 0; i < 4; i++)
#pragma unroll
        for (int j = 0; j < 4; j++) acc[i][j] = (f32x4)0.f;

    for (int kk = 0; kk < D_FF; kk += BK) {
        // A: h rows, already bf16: 128 rows x 32 bf16 = 4 x 16B per row
#pragma unroll
        for (int l = 0; l < 2; l++) {
            int idx = tid + l * 256;
            int r = idx >> 2, s = idx & 3;
            int rr = m0 + r;
            if (rr > cnt - 1) rr = cnt - 1;
            uint4 v = *(const uint4*)(hbuf + (size_t)(base + rr) * D_FF + kk + s * 8);
            *(uint4*)&As[r * SP + s * 8] = v;
        }
        // B: W2 rows (out dim), fp32 -> bf16
#pragma unroll
        for (int l = 0; l < 4; l++) {
            int idx = tid + l * 256;
            int r = idx >> 3, s = idx & 7;
            float4 v = *(const float4*)(w2 + (size_t)(n0 + r) * D_FF + kk + s * 4);
            unsigned short* d = &Bs[r * SP + s * 4];
            d[0] = f2bf(v.x); d[1] = f2bf(v.y); d[2] = f2bf(v.z); d[3] = f2bf(v.w);
        }
        __syncthreads();

        bf16x8 aF[4], bF[4];
#pragma unroll
        for (int mi = 0; mi < 4; mi++)
            aF[mi] = *(const bf16x8*)&As[(wm + mi * 16 + lm) * SP + lq * 8];
#pragma unroll
        for (int ni = 0; ni < 4; ni++)
            bF[ni] = *(const bf16x8*)&Bs[(wn + ni * 16 + lm) * SP + lq * 8];
#pragma unroll
        for (int mi = 0; mi < 4; mi++)
#pragma unroll
            for (int ni = 0; ni < 4; ni++)
                acc[mi][ni] = __builtin_amdgcn_mfma_f32_16x16x32_bf16(aF[mi], bF[ni], acc[mi][ni], 0, 0, 0);
        __syncthreads();
    }

#pragma unroll
    for (int mi = 0; mi < 4; mi++) {
#pragma unroll
        for (int r = 0; r < 4; r++) {
            int mrow = wm + mi * 16 + lq * 4 + r;
            if (m0 + mrow < cnt) {
                int   t = tok[mrow];
                float p = prb[mrow];
                float* op = out + (size_t)t * D_MODEL + n0 + wn;
#pragma unroll
                for (int ni = 0; ni < 4; ni++)
                    atomicAdd(&op[ni * 16 + lm], p * acc[mi][ni][r]);
            }
        }
    }
}

extern "C" void kernel_launch(void* const* d_in, const int* in_sizes, int n_in,
                              void* d_out, int out_size, void* d_ws, size_t ws_size,
                              hipStream_t stream) {
    const float* x  = (const float*)d_in[0];
    const float* gW = (const float*)d_in[1];
    const float* gb = (const float*)d_in[2];
    const float* Wg = (const float*)d_in[3];
    const float* W1 = (const float*)d_in[4];
    const float* W2 = (const float*)d_in[5];
    float* out = (float*)d_out;

    char* ws = (char*)d_ws;
    // layout: [0,32) counts | [64,96) offsets | [128,160) cursor | [256, +64K) row_map
    //         | +64K row_prob | +64K top_e | +64K top_p | then hbuf (134.2 MB)
    int*   counts   = (int*)ws;
    int*   offsets  = (int*)(ws + 64);
    int*   cursor   = (int*)(ws + 128);
    int*   row_map  = (int*)(ws + 256);
    float* row_prob = (float*)(ws + 256 + 65536);
    int*   top_e    = (int*)(ws + 256 + 2 * 65536);
    float* top_p    = (float*)(ws + 256 + 3 * 65536);
    unsigned short* hbuf = (unsigned short*)(ws + 256 + 4 * 65536);  // 2*T * D_FF bf16

    hipMemsetAsync(ws, 0, 256, stream);
    hipMemsetAsync(d_out, 0, (size_t)T_TOKENS * D_MODEL * sizeof(float), stream);

    router_kernel<<<T_TOKENS / 4, 256, 0, stream>>>(x, gW, gb, counts, top_e, top_p);
    prefix_kernel<<<1, 64, 0, stream>>>(counts, offsets, cursor);
    scatter_kernel<<<T_TOKENS / 256, 256, 0, stream>>>(top_e, top_p, cursor, row_map, row_prob);
    gemm1_kernel<<<dim3(D_FF / BN, T_TOKENS / BM, N_EXP), 256, 0, stream>>>(
        x, Wg, W1, counts, offsets, row_map, hbuf);
    gemm2_kernel<<<dim3(D_MODEL / BN, T_TOKENS / BM, N_EXP), 256, 0, stream>>>(
        hbuf, W2, counts, offsets, row_map, row_prob, out);
}

// Round 2
// 1300.236 us; speedup vs baseline: 1.0669x; 1.0669x over previous
//
#include <hip/hip_runtime.h>

#define T_TOKENS 8192
#define D_MODEL  1024
#define D_FF     4096
#define N_EXP    8

#define BM 128
#define BN 128
#define BK 32

typedef __attribute__((ext_vector_type(8))) short bf16x8;
typedef __attribute__((ext_vector_type(4))) float f32x4;

__device__ __forceinline__ unsigned short f2bf(float f) {
    unsigned int u = __float_as_uint(f);
    u += 0x7fffu + ((u >> 16) & 1u);   // RNE
    return (unsigned short)(u >> 16);
}

// async global->LDS, 16B per lane; LDS dest = wave-uniform base + lane*16
__device__ __forceinline__ void gld16(const unsigned short* g, unsigned short* l) {
    __builtin_amdgcn_global_load_lds(
        (const __attribute__((address_space(1))) unsigned int*)g,
        (__attribute__((address_space(3))) unsigned int*)l, 16, 0, 0);
}

// ---------------- fp32 -> bf16 bulk convert (8 elems/thread) ----------------
__global__ void cvt_kernel(const float* __restrict__ src, unsigned short* __restrict__ dst) {
    size_t i = ((size_t)blockIdx.x * 256 + threadIdx.x) * 8;
    float4 a = *(const float4*)(src + i);
    float4 b = *(const float4*)(src + i + 4);
    union { unsigned short u[8]; uint4 v; } r;
    r.u[0] = f2bf(a.x); r.u[1] = f2bf(a.y); r.u[2] = f2bf(a.z); r.u[3] = f2bf(a.w);
    r.u[4] = f2bf(b.x); r.u[5] = f2bf(b.y); r.u[6] = f2bf(b.z); r.u[7] = f2bf(b.w);
    *(uint4*)(dst + i) = r.v;
}

// ---------------- router: logits, top-2, softmax, counts ----------------
__global__ void router_kernel(const float* __restrict__ x, const float* __restrict__ gW,
                              const float* __restrict__ gb, int* __restrict__ counts,
                              int* __restrict__ top_e, float* __restrict__ top_p) {
    int t    = blockIdx.x * 4 + (threadIdx.x >> 6);
    int lane = threadIdx.x & 63;
    const float* xr = x + (size_t)t * D_MODEL;
    float acc[N_EXP];
#pragma unroll
    for (int e = 0; e < N_EXP; e++) acc[e] = 0.f;
    for (int i = 0; i < D_MODEL / 64; i++) {
        float xv = xr[lane + i * 64];
#pragma unroll
        for (int e = 0; e < N_EXP; e++) acc[e] += xv * gW[e * D_MODEL + lane + i * 64];
    }
#pragma unroll
    for (int e = 0; e < N_EXP; e++) {
#pragma unroll
        for (int off = 32; off > 0; off >>= 1) acc[e] += __shfl_down(acc[e], off, 64);
    }
    if (lane == 0) {
#pragma unroll
        for (int e = 0; e < N_EXP; e++) acc[e] += gb[e];
        int e0 = 0;
#pragma unroll
        for (int e = 1; e < N_EXP; e++) if (acc[e] > acc[e0]) e0 = e;  // ties -> lowest idx
        int e1 = (e0 == 0) ? 1 : 0;
#pragma unroll
        for (int e = 0; e < N_EXP; e++) if (e != e0 && e != e1 && acc[e] > acc[e1]) e1 = e;
        float z1 = __expf(acc[e1] - acc[e0]);
        float s  = 1.f + z1;
        top_e[t * 2]     = e0;
        top_e[t * 2 + 1] = e1;
        top_p[t * 2]     = 1.f / s;
        top_p[t * 2 + 1] = z1 / s;
        atomicAdd(&counts[e0], 1);
        atomicAdd(&counts[e1], 1);
    }
}

__global__ void prefix_kernel(const int* __restrict__ counts, int* __restrict__ offsets,
                              int* __restrict__ cursor) {
    if (threadIdx.x == 0) {
        int s = 0;
        for (int e = 0; e < N_EXP; e++) { offsets[e] = s; cursor[e] = s; s += counts[e]; }
    }
}

__global__ void scatter_kernel(const int* __restrict__ top_e, const float* __restrict__ top_p,
                               int* __restrict__ cursor, int* __restrict__ row_map,
                               float* __restrict__ row_prob) {
    int t = blockIdx.x * 256 + threadIdx.x;
#pragma unroll
    for (int j = 0; j < 2; j++) {
        int e  = top_e[t * 2 + j];
        int pos = atomicAdd(&cursor[e], 1);
        row_map[pos]  = t;
        row_prob[pos] = top_p[t * 2 + j];
    }
}

// ---------------- gather x rows into expert-sorted bf16 ----------------
__global__ void gather_x_kernel(const float* __restrict__ x, const int* __restrict__ row_map,
                                unsigned short* __restrict__ xg) {
    int pos = blockIdx.x * 2 + (threadIdx.x >> 7);
    int c   = (threadIdx.x & 127) * 8;
    int t   = row_map[pos];
    float4 a = *(const float4*)(x + (size_t)t * D_MODEL + c);
    float4 b = *(const float4*)(x + (size_t)t * D_MODEL + c + 4);
    union { unsigned short u[8]; uint4 v; } r;
    r.u[0] = f2bf(a.x); r.u[1] = f2bf(a.y); r.u[2] = f2bf(a.z); r.u[3] = f2bf(a.w);
    r.u[4] = f2bf(b.x); r.u[5] = f2bf(b.y); r.u[6] = f2bf(b.z); r.u[7] = f2bf(b.w);
    *(uint4*)(xg + (size_t)pos * D_MODEL + c) = r.v;
}

// LDS layout for a 128row x 32k bf16 tile: cell = row*4 + (kb ^ (row&3)), each cell 8 bf16 (16B).
// global_load_lds: lane cell = wave*64 + l*256 + lane; global side stays 64B-line coalesced,
// ds_read side is <=2-way bank aliased (free).

// ---------------- gemm1: h = prob * silu(xg@Wg^T) * (xg@W1^T), bf16 out -------------
__launch_bounds__(256, 2)
__global__ void gemm1_kernel(const unsigned short* __restrict__ xg,
                             const unsigned short* __restrict__ wgb,
                             const unsigned short* __restrict__ w1b,
                             const int* __restrict__ counts, const int* __restrict__ offsets,
                             const float* __restrict__ row_prob,
                             unsigned short* __restrict__ hbuf) {
    int e   = blockIdx.z;
    int cnt = counts[e];
    int m0  = blockIdx.y * BM;
    if (m0 >= cnt) return;
    int base = offsets[e];
    int n0   = blockIdx.x * BN;
    int tid  = threadIdx.x;
    int wave = tid >> 6, lane = tid & 63;

    __shared__ unsigned short As[BM * BK];
    __shared__ unsigned short Bg[BN * BK];
    __shared__ unsigned short Bv[BN * BK];
    __shared__ float prb[BM];

    if (tid < BM) {
        int i = m0 + tid; if (i > cnt - 1) i = cnt - 1;
        prb[tid] = row_prob[base + i];
    }

    const unsigned short* wg = wgb + (size_t)e * D_FF * D_MODEL;
    const unsigned short* w1 = w1b + (size_t)e * D_FF * D_MODEL;

    const unsigned short* gA[2]; const unsigned short* gG[2]; const unsigned short* gV[2];
    unsigned short* lA[2]; unsigned short* lG[2]; unsigned short* lV[2];
#pragma unroll
    for (int l = 0; l < 2; l++) {
        int cell = wave * 64 + l * 256 + lane;
        int row  = cell >> 2;
        int kb   = (cell & 3) ^ (row & 3);
        int ra = m0 + row; if (ra > cnt - 1) ra = cnt - 1;
        gA[l] = xg + (size_t)(base + ra) * D_MODEL + kb * 8;
        gG[l] = wg + (size_t)(n0 + row) * D_MODEL + kb * 8;
        gV[l] = w1 + (size_t)(n0 + row) * D_MODEL + kb * 8;
        int c0 = wave * 64 + l * 256;
        lA[l] = As + c0 * 8;
        lG[l] = Bg + c0 * 8;
        lV[l] = Bv + c0 * 8;
    }

    int wm = (wave >> 1) * 64, wn = (wave & 1) * 64;
    int lm = lane & 15, lq = lane >> 4;
    int swz = lq ^ (lm & 3);
    const bf16x8* aP = (const bf16x8*)(As + ((wm + lm) * 4 + swz) * 8);
    const bf16x8* gP = (const bf16x8*)(Bg + ((wn + lm) * 4 + swz) * 8);
    const bf16x8* vP = (const bf16x8*)(Bv + ((wn + lm) * 4 + swz) * 8);

    f32x4 accG[4][4], accV[4][4];
#pragma unroll
    for (int i = 0; i < 4; i++)
#pragma unroll
        for (int j = 0; j < 4; j++) { accG[i][j] = (f32x4)0.f; accV[i][j] = (f32x4)0.f; }

    for (int kk = 0; kk < D_MODEL; kk += BK) {
        gld16(gA[0], lA[0]); gld16(gA[1], lA[1]);
        gld16(gG[0], lG[0]); gld16(gG[1], lG[1]);
        gld16(gV[0], lV[0]); gld16(gV[1], lV[1]);
        gA[0] += BK; gA[1] += BK; gG[0] += BK; gG[1] += BK; gV[0] += BK; gV[1] += BK;
        __syncthreads();

        bf16x8 aF[4], bgF[4], bvF[4];
#pragma unroll
        for (int mi = 0; mi < 4; mi++) aF[mi] = aP[mi * 64];
#pragma unroll
        for (int ni = 0; ni < 4; ni++) { bgF[ni] = gP[ni * 64]; bvF[ni] = vP[ni * 64]; }
#pragma unroll
        for (int mi = 0; mi < 4; mi++)
#pragma unroll
            for (int ni = 0; ni < 4; ni++) {
                accG[mi][ni] = __builtin_amdgcn_mfma_f32_16x16x32_bf16(aF[mi], bgF[ni], accG[mi][ni], 0, 0, 0);
                accV[mi][ni] = __builtin_amdgcn_mfma_f32_16x16x32_bf16(aF[mi], bvF[ni], accV[mi][ni], 0, 0, 0);
            }
        __syncthreads();
    }

    size_t hrow_base = (size_t)(base + m0);
#pragma unroll
    for (int mi = 0; mi < 4; mi++) {
#pragma unroll
        for (int r = 0; r < 4; r++) {
            int mrow = wm + mi * 16 + lq * 4 + r;
            if (m0 + mrow < cnt) {
                float p = prb[mrow];
                unsigned short* hp = hbuf + (hrow_base + mrow) * D_FF + n0 + wn;
#pragma unroll
                for (int ni = 0; ni < 4; ni++) {
                    float g = accG[mi][ni][r], v = accV[mi][ni][r];
                    float sg = g / (1.f + __expf(-g));
                    hp[ni * 16 + lm] = f2bf(sg * v * p);
                }
            }
        }
    }
}

// ---------------- gemm2: out[token] += (h @ W2^T)  (prob folded into h) ----------------
__launch_bounds__(256, 2)
__global__ void gemm2_kernel(const unsigned short* __restrict__ hbuf,
                             const unsigned short* __restrict__ w2b,
                             const int* __restrict__ counts, const int* __restrict__ offsets,
                             const int* __restrict__ row_map,
                             float* __restrict__ out) {
    int e   = blockIdx.z;
    int cnt = counts[e];
    int m0  = blockIdx.y * BM;
    if (m0 >= cnt) return;
    int base = offsets[e];
    int n0   = blockIdx.x * BN;
    int tid  = threadIdx.x;
    int wave = tid >> 6, lane = tid & 63;

    __shared__ unsigned short As[BM * BK];
    __shared__ unsigned short Bs[BN * BK];
    __shared__ int tok[BM];

    if (tid < BM) {
        int i = m0 + tid; if (i > cnt - 1) i = cnt - 1;
        tok[tid] = row_map[base + i];
    }

    const unsigned short* w2 = w2b + (size_t)e * D_MODEL * D_FF;

    const unsigned short* gA[2]; const unsigned short* gB[2];
    unsigned short* lA[2]; unsigned short* lB[2];
#pragma unroll
    for (int l = 0; l < 2; l++) {
        int cell = wave * 64 + l * 256 + lane;
        int row  = cell >> 2;
        int kb   = (cell & 3) ^ (row & 3);
        int ra = m0 + row; if (ra > cnt - 1) ra = cnt - 1;
        gA[l] = hbuf + (size_t)(base + ra) * D_FF + kb * 8;
        gB[l] = w2 + (size_t)(n0 + row) * D_FF + kb * 8;
        int c0 = wave * 64 + l * 256;
        lA[l] = As + c0 * 8;
        lB[l] = Bs + c0 * 8;
    }

    int wm = (wave >> 1) * 64, wn = (wave & 1) * 64;
    int lm = lane & 15, lq = lane >> 4;
    int swz = lq ^ (lm & 3);
    const bf16x8* aP = (const bf16x8*)(As + ((wm + lm) * 4 + swz) * 8);
    const bf16x8* bP = (const bf16x8*)(Bs + ((wn + lm) * 4 + swz) * 8);

    f32x4 acc[4][4];
#pragma unroll
    for (int i = 0; i < 4; i++)
#pragma unroll
        for (int j = 0; j < 4; j++) acc[i][j] = (f32x4)0.f;

    for (int kk = 0; kk < D_FF; kk += BK) {
        gld16(gA[0], lA[0]); gld16(gA[1], lA[1]);
        gld16(gB[0], lB[0]); gld16(gB[1], lB[1]);
        gA[0] += BK; gA[1] += BK; gB[0] += BK; gB[1] += BK;
        __syncthreads();

        bf16x8 aF[4], bF[4];
#pragma unroll
        for (int mi = 0; mi < 4; mi++) aF[mi] = aP[mi * 64];
#pragma unroll
        for (int ni = 0; ni < 4; ni++) bF[ni] = bP[ni * 64];
#pragma unroll
        for (int mi = 0; mi < 4; mi++)
#pragma unroll
            for (int ni = 0; ni < 4; ni++)
                acc[mi][ni] = __builtin_amdgcn_mfma_f32_16x16x32_bf16(aF[mi], bF[ni], acc[mi][ni], 0, 0, 0);
        __syncthreads();
    }

#pragma unroll
    for (int mi = 0; mi < 4; mi++) {
#pragma unroll
        for (int r = 0; r < 4; r++) {
            int mrow = wm + mi * 16 + lq * 4 + r;
            if (m0 + mrow < cnt) {
                int t = tok[mrow];
                float* op = out + (size_t)t * D_MODEL + n0 + wn;
#pragma unroll
                for (int ni = 0; ni < 4; ni++)
                    atomicAdd(&op[ni * 16 + lm], acc[mi][ni][r]);
            }
        }
    }
}

extern "C" void kernel_launch(void* const* d_in, const int* in_sizes, int n_in,
                              void* d_out, int out_size, void* d_ws, size_t ws_size,
                              hipStream_t stream) {
    const float* x  = (const float*)d_in[0];
    const float* gW = (const float*)d_in[1];
    const float* gb = (const float*)d_in[2];
    const float* Wg = (const float*)d_in[3];
    const float* W1 = (const float*)d_in[4];
    const float* W2 = (const float*)d_in[5];
    float* out = (float*)d_out;

    char* ws = (char*)d_ws;
    const size_t MiB = 1024 * 1024;
    int*   counts   = (int*)ws;
    int*   offsets  = (int*)(ws + 64);
    int*   cursor   = (int*)(ws + 128);
    int*   row_map  = (int*)(ws + 256);
    float* row_prob = (float*)(ws + 256 + 65536);
    int*   top_e    = (int*)(ws + 256 + 2 * 65536);
    float* top_p    = (float*)(ws + 256 + 3 * 65536);
    unsigned short* wgb  = (unsigned short*)(ws + 1 * MiB);     // 64 MiB bf16 Wg
    unsigned short* w1b  = (unsigned short*)(ws + 65 * MiB);    // 64 MiB bf16 W1
    unsigned short* xg   = (unsigned short*)(ws + 129 * MiB);   // 32 MiB bf16 gathered x
    unsigned short* hbuf = (unsigned short*)(ws + 161 * MiB);   // 128 MiB bf16 h
    unsigned short* w2b  = wgb;  // alias: Wg bf16 is dead after gemm1

    hipMemsetAsync(ws, 0, 256, stream);
    hipMemsetAsync(d_out, 0, (size_t)T_TOKENS * D_MODEL * sizeof(float), stream);

    cvt_kernel<<<16384, 256, 0, stream>>>(Wg, wgb);
    cvt_kernel<<<16384, 256, 0, stream>>>(W1, w1b);
    router_kernel<<<T_TOKENS / 4, 256, 0, stream>>>(x, gW, gb, counts, top_e, top_p);
    prefix_kernel<<<1, 64, 0, stream>>>(counts, offsets, cursor);
    scatter_kernel<<<T_TOKENS / 256, 256, 0, stream>>>(top_e, top_p, cursor, row_map, row_prob);
    gather_x_kernel<<<T_TOKENS, 256, 0, stream>>>(x, row_map, xg);
    gemm1_kernel<<<dim3(D_FF / BN, T_TOKENS / BM, N_EXP), 256, 0, stream>>>(
        xg, wgb, w1b, counts, offsets, row_prob, hbuf);
    cvt_kernel<<<16384, 256, 0, stream>>>(W2, w2b);
    gemm2_kernel<<<dim3(D_MODEL / BN, T_TOKENS / BM, N_EXP), 256, 0, stream>>>(
        hbuf, w2b, counts, offsets, row_map, out);
}